// Round 8
// baseline (489.527 us; speedup 1.0000x reference)
//
#include <hip/hip_runtime.h>

typedef short s8v  __attribute__((ext_vector_type(8)));
typedef float f4v  __attribute__((ext_vector_type(4)));
typedef int   v4i  __attribute__((ext_vector_type(4)));
typedef float v4f  __attribute__((ext_vector_type(4)));
typedef int   v2i  __attribute__((ext_vector_type(2)));

#define NNODES 8192
#define FDIM   256
#define NJC    4          // j-chunks; grid 512 = 2 blocks/CU (R2-best TLP)
#define JLEN   2048       // columns-j per chunk
#define TROWS  64         // rows per block
#define KSTEP  32         // k per step = one PB k-tile
#define NSTEP  64         // JLEN / KSTEP
#define RSTR   ((size_t)16 * NNODES)   // adj row-halfstep stride (16 rows)

__device__ __forceinline__ unsigned short f2bf(float f) {
    unsigned int x = __builtin_bit_cast(unsigned int, f);
    x += 0x7fffu + ((x >> 16) & 1u);
    return (unsigned short)(x >> 16);
}
// RTNE pack of 2 f32 -> 1 dword of 2 bf16
__device__ __forceinline__ int cvt_pk(float lo, float hi) {
    int r;
    asm("v_cvt_pk_bf16_f32 %0, %1, %2" : "=v"(r) : "v"(lo), "v"(hi));
    return r;
}

// ---------------- Kernel 0: fused WT + wv ----------------
__global__ __launch_bounds__(256) void prep_kernel(const float* __restrict__ W,
                                                   const float* __restrict__ a,
                                                   unsigned short* __restrict__ WT,
                                                   float* __restrict__ v1,
                                                   float* __restrict__ v2) {
    if (blockIdx.x < 256) {
        int idx = blockIdx.x * 256 + threadIdx.x;
        int r = idx >> 8, c = idx & 255;
        WT[c * 256 + r] = f2bf(W[r * 256 + c]);
    } else {
        __shared__ float r1[256], r2[256];
        int b = blockIdx.x - 256, n = threadIdx.x;
        float w = W[(size_t)b * FDIM + n];
        r1[n] = w * a[n];
        r2[n] = w * a[FDIM + n];
        __syncthreads();
        for (int off = 128; off > 0; off >>= 1) {
            if (n < off) { r1[n] += r1[n + off]; r2[n] += r2[n + off]; }
            __syncthreads();
        }
        if (n == 0) { v1[b] = r1[0]; v2[b] = r2[0]; }
    }
}

// ---------------- Kernel 1: PB = tiled bf16 Wh; s1/s2 = h@v (fp32) ----------------
__global__ __launch_bounds__(128) void wh_kernel(
    const float* __restrict__ h, const unsigned short* __restrict__ WT,
    const float* __restrict__ v1, const float* __restrict__ v2,
    unsigned short* __restrict__ PB,
    float* __restrict__ s1, float* __restrict__ s2)
{
    __shared__ float v1_lds[FDIM], v2_lds[FDIM];
    int tid = threadIdx.x;
    v1_lds[tid] = v1[tid];       v1_lds[tid + 128] = v1[tid + 128];
    v2_lds[tid] = v2[tid];       v2_lds[tid + 128] = v2[tid + 128];
    __syncthreads();

    int w = tid >> 6, lane = tid & 63, q = lane >> 4, l15 = lane & 15;
    int i_base = blockIdx.x * 32 + w * 16;

    f4v acc[16] = {};
    float s1p = 0.f, s2p = 0.f;

    for (int k0 = 0; k0 < 256; k0 += 32) {
        const float* hp = h + (size_t)(i_base + l15) * FDIM + k0 + q * 8;
        f4v h0 = *(const f4v*)hp;
        f4v h1 = *(const f4v*)(hp + 4);
        union { v4i u; s8v s; } af;
        af.u[0] = cvt_pk(h0[0], h0[1]);
        af.u[1] = cvt_pk(h0[2], h0[3]);
        af.u[2] = cvt_pk(h1[0], h1[1]);
        af.u[3] = cvt_pk(h1[2], h1[3]);
#pragma unroll
        for (int j = 0; j < 4; ++j) {
            s1p += h0[j] * v1_lds[k0 + q * 8 + j] + h1[j] * v1_lds[k0 + q * 8 + 4 + j];
            s2p += h0[j] * v2_lds[k0 + q * 8 + j] + h1[j] * v2_lds[k0 + q * 8 + 4 + j];
        }
#pragma unroll
        for (int t = 0; t < 16; ++t) {
            s8v bf = *(const s8v*)(WT + (size_t)(t * 16 + l15) * FDIM + k0 + q * 8);
            acc[t] = __builtin_amdgcn_mfma_f32_16x16x32_bf16(af.s, bf, acc[t], 0, 0, 0);
        }
    }

    s1p += __shfl_xor(s1p, 16, 64);
    s1p += __shfl_xor(s1p, 32, 64);
    s2p += __shfl_xor(s2p, 16, 64);
    s2p += __shfl_xor(s2p, 32, 64);
    if (lane < 16) {
        s1[i_base + lane] = s1p;
        s2[i_base + lane] = s2p;
    }

#pragma unroll
    for (int t = 0; t < 16; ++t) {
        int i0 = i_base + q * 4;
        size_t a16 = (size_t)((i0 >> 5) * 16 + t) * 512
                   + l15 * 32 + ((i0 >> 3) & 3) * 8 + (i0 & 7);
        v2i pk;
        pk[0] = cvt_pk(acc[t][0], acc[t][1]);
        pk[1] = cvt_pk(acc[t][2], acc[t][3]);
        *(v2i*)(PB + a16) = pk;
    }
}

// ---------------- Kernel 2: zero-barrier split-K attention ----------------
// R16: every variant sharing the per-step LDS P-handoff (R2/R5/R6) plateaued
// identically -> eliminate the handoff. Each wave computes its OWN A-frags
// in registers: lane (q,l15) computes P[rh*16+l15][q*8..+7] directly from
// adj + s1 + s2 (32 exps/lane/step; 4x redundant across waves but v_exp is
// quarter-rate 1-instr => ~28us chip-wide, affordable). NO P_lds, NO in-loop
// barriers; each wave free-runs with depth-2 adj prefetch (~1000cy slack vs
// ~900cy HBM) and bf double-buffer. adj read by all 4 waves at the same
// addresses -> L1-broadcast (8KB/step << 32KB L1), so loads are cacheable
// (nontemporal dropped). jc=bid&3 pins one 1-MiB PB slice per XCD.
// 2 blocks/CU = 2 waves/SIMD (R2-best TLP); VGPR ~200 < 256 cap of (256,2).
__global__ __launch_bounds__(256, 2) void attn_partial(
    const int* __restrict__ adj, const unsigned short* __restrict__ PB,
    const float* __restrict__ s1, const float* __restrict__ s2,
    float* __restrict__ Npart, float* __restrict__ dpart)
{
    __shared__ float s2_lds[JLEN];   // 8 KB (only LDS use)

    int tid = threadIdx.x;
    int jc = blockIdx.x & 3, rt = blockIdx.x >> 2;
    int j0 = jc * JLEN;

    for (int i = tid; i < JLEN / 4; i += 256)
        ((v4f*)s2_lds)[i] = ((const v4f*)(s2 + j0))[i];

    int g = tid >> 6, lane = tid & 63, q = lane >> 4, l15 = lane & 15;

    // s1 for this lane's 4 rows (rh*16 + l15)
    float s1r[4];
#pragma unroll
    for (int rh = 0; rh < 4; ++rh) s1r[rh] = s1[rt * TROWS + rh * 16 + l15];

    const unsigned short* pbb = PB + (size_t)(jc * NSTEP) * 16 * 512 + l15 * 32 + q * 8;
    const int* arow = adj + (size_t)(rt * TROWS + l15) * NNODES + j0 + q * 8;

    f4v acc[4][4] = {};
    float dsum4[4] = {0.f, 0.f, 0.f, 0.f};

    __syncthreads();  // s2 staged -- the only barrier

    // prologue: adj for steps 0 (aA) and 1 (aB); bf frags for step 0 (bfA)
    v4i aA[4][2], aB[4][2];
#pragma unroll
    for (int rh = 0; rh < 4; ++rh) {
        const int* pp = arow + rh * RSTR;
        aA[rh][0] = *(const v4i*)(pp);
        aA[rh][1] = *(const v4i*)(pp + 4);
        aB[rh][0] = *(const v4i*)(pp + KSTEP);
        aB[rh][1] = *(const v4i*)(pp + KSTEP + 4);
    }
    s8v bfA[4], bfB[4];
#pragma unroll
    for (int t = 0; t < 4; ++t)
        bfA[t] = *(const s8v*)(pbb + (size_t)(g * 4 + t) * 512);

// One step: consume AC (adj for S) + BC (bf for S); issue bf for S+1 into BN
// and adj for S+2 back into AC (depth-2, ~2 steps in flight). No barriers.
#define ASTEP(S, AC, BC, BN) do {                                             \
    int sc = (S);                                                             \
    v4f svA = *(const v4f*)&s2_lds[sc * KSTEP + q * 8];                       \
    v4f svB = *(const v4f*)&s2_lds[sc * KSTEP + q * 8 + 4];                   \
    int sb = (sc + 1 < NSTEP) ? sc + 1 : 0;                                   \
    _Pragma("unroll")                                                         \
    for (int t = 0; t < 4; ++t)                                               \
        BN[t] = *(const s8v*)(pbb + (size_t)(sb * 16 + g * 4 + t) * 512);     \
    int sn = (sc + 2 < NSTEP) ? sc + 2 : 0;                                   \
    _Pragma("unroll")                                                         \
    for (int rh = 0; rh < 4; ++rh) {                                          \
        float pa[8];                                                          \
        _Pragma("unroll")                                                     \
        for (int j = 0; j < 4; ++j) {                                         \
            float x = s1r[rh] + svA[j];                                       \
            pa[j] = (AC[rh][0][j] > 0) ? __expf(fmaxf(x, 0.2f * x)) : 0.0f;   \
            float x2 = s1r[rh] + svB[j];                                      \
            pa[4 + j] = (AC[rh][1][j] > 0) ? __expf(fmaxf(x2, 0.2f * x2)) : 0.0f; \
            dsum4[rh] += pa[j] + pa[4 + j];                                   \
        }                                                                     \
        union { v4i u; s8v s; } af;                                           \
        af.u[0] = cvt_pk(pa[0], pa[1]);  af.u[1] = cvt_pk(pa[2], pa[3]);      \
        af.u[2] = cvt_pk(pa[4], pa[5]);  af.u[3] = cvt_pk(pa[6], pa[7]);      \
        _Pragma("unroll")                                                     \
        for (int t = 0; t < 4; ++t)                                           \
            acc[rh][t] = __builtin_amdgcn_mfma_f32_16x16x32_bf16(af.s, BC[t], acc[rh][t], 0, 0, 0); \
        const int* pp = arow + rh * RSTR + (size_t)sn * KSTEP;                \
        AC[rh][0] = *(const v4i*)(pp);                                        \
        AC[rh][1] = *(const v4i*)(pp + 4);                                    \
    }                                                                         \
} while (0)

    for (int s = 0; s < NSTEP; s += 2) {
        ASTEP(s,     aA, bfA, bfB);
        ASTEP(s + 1, aB, bfB, bfA);
    }
#undef ASTEP

    // denominator: all 4 waves hold identical P => identical sums; reduce
    // each lane's q-slice partial across q (lane bits 4,5), wave 0 writes.
#pragma unroll
    for (int rh = 0; rh < 4; ++rh) {
        dsum4[rh] += __shfl_xor(dsum4[rh], 16, 64);
        dsum4[rh] += __shfl_xor(dsum4[rh], 32, 64);
    }
    if (g == 0 && lane < 16) {
#pragma unroll
        for (int rh = 0; rh < 4; ++rh)
            dpart[jc * NNODES + rt * TROWS + rh * 16 + lane] = dsum4[rh];
    }

    // partial numerator: row = rh*16 + q*4 + r, col = g*64 + t*16 + l15
#pragma unroll
    for (int rh = 0; rh < 4; ++rh)
#pragma unroll
        for (int r = 0; r < 4; ++r) {
            int row = rh * 16 + q * 4 + r;
            float* base = Npart + ((size_t)(jc * NNODES) + rt * TROWS + row) * FDIM;
#pragma unroll
            for (int t = 0; t < 4; ++t)
                __builtin_nontemporal_store(acc[rh][t][r], base + g * 64 + t * 16 + l15);
        }
}

// ---------------- Kernel 3: reduce partials, normalize ----------------
__global__ __launch_bounds__(256) void reduce_kernel(
    const float* __restrict__ Npart, const float* __restrict__ dpart,
    float* __restrict__ out)
{
    int i = blockIdx.x, n = threadIdx.x;
    float d = 0.f, acc = 0.f;
#pragma unroll
    for (int jc = 0; jc < NJC; ++jc) {
        d += dpart[jc * NNODES + i];
        acc += Npart[((size_t)(jc * NNODES) + i) * FDIM + n];
    }
    out[(size_t)i * FDIM + n] = acc / fmaxf(d, 1e-30f);
}

extern "C" void kernel_launch(void* const* d_in, const int* in_sizes, int n_in,
                              void* d_out, int out_size, void* d_ws, size_t ws_size,
                              hipStream_t stream) {
    const float* h   = (const float*)d_in[0];
    const int*   adj = (const int*)d_in[1];
    const float* W   = (const float*)d_in[2];
    const float* a   = (const float*)d_in[3];
    float* out = (float*)d_out;

    char* ws = (char*)d_ws;
    unsigned short* PB = (unsigned short*)ws;                  // 4 MiB (tiled Wh)
    float* s1 = (float*)(ws + (4u << 20));                     // 32 KiB
    float* s2 = (float*)(ws + (4u << 20) + (32u << 10));       // 32 KiB
    unsigned short* WT = (unsigned short*)(ws + (4u << 20) + (64u << 10));   // 128 KiB
    float* v1 = (float*)(ws + (4u << 20) + (192u << 10));      // 1 KiB
    float* v2 = (float*)(ws + (4u << 20) + (193u << 10));      // 1 KiB
    float* dpart = (float*)(ws + (5u << 20));                  // 128 KiB
    float* Npart = (float*)(ws + (8u << 20));                  // 32 MiB

    hipLaunchKernelGGL(prep_kernel, dim3(512), dim3(256), 0, stream, W, a, WT, v1, v2);
    hipLaunchKernelGGL(wh_kernel, dim3(256), dim3(128), 0, stream, h, WT, v1, v2, PB, s1, s2);
    hipLaunchKernelGGL(attn_partial, dim3(128 * NJC), dim3(256), 0, stream,
                       adj, PB, s1, s2, Npart, dpart);
    hipLaunchKernelGGL(reduce_kernel, dim3(NNODES), dim3(256), 0, stream, Npart, dpart, out);
}